// Round 1
// baseline (19331.381 us; speedup 1.0000x reference)
//
#include <hip/hip_runtime.h>
#include <stdint.h>

#define TT    8192
#define EMBD  128
#define HID   256
#define G4    1024      // 4*HID
#define NTAGS 17
#define NBLK  16        // recurrence workgroups
#define SH    16        // HID / NBLK  (h elements owned per block)

__device__ __forceinline__ float sigf(float x) { return 1.f / (1.f + __expf(-x)); }
__device__ __forceinline__ float tanhf_fast(float x) {
    x = fminf(15.f, fmaxf(-15.f, x));
    float a = __expf(2.f * x);
    return (a - 1.f) / (a + 1.f);
}

// ---------------------------------------------------------------------------
// Kernel A: xg[t][j] = dot(emb[tok[t]], W_ih[j]) + b_ih[j] + b_hh[j]
// 4 tokens per block (amortizes W_ih reads), 256 threads, thread -> 4 rows.
// Also zeroes the per-step barrier counters (block 0) before the lstm kernel.
// ---------------------------------------------------------------------------
__global__ __launch_bounds__(256) void xg_kernel(
    const int* __restrict__ tok, const float* __restrict__ emb,
    const float* __restrict__ Wih, const float* __restrict__ bih,
    const float* __restrict__ bhh, float* __restrict__ xg,
    unsigned int* __restrict__ cnt)
{
    __shared__ __align__(16) float es[4][EMBD];
    const int tid = threadIdx.x;
    const int t0  = blockIdx.x * 4;

    if (blockIdx.x == 0) {
        for (int i = tid; i < TT; i += 256) cnt[i] = 0u;
    }
    for (int p = tid; p < 4 * EMBD; p += 256) {
        const int tt = p >> 7, k = p & 127;
        es[tt][k] = emb[(long)tok[t0 + tt] * EMBD + k];
    }
    __syncthreads();

#pragma unroll
    for (int q = 0; q < 4; ++q) {
        const int j = q * 256 + tid;
        const float4* wr = (const float4*)(Wih + (long)j * EMBD);
        float a0 = 0.f, a1 = 0.f, a2 = 0.f, a3 = 0.f;
#pragma unroll 8
        for (int k4 = 0; k4 < EMBD / 4; ++k4) {
            const float4 w  = wr[k4];
            const float4 e0 = ((const float4*)es[0])[k4];
            const float4 e1 = ((const float4*)es[1])[k4];
            const float4 e2 = ((const float4*)es[2])[k4];
            const float4 e3 = ((const float4*)es[3])[k4];
            a0 += w.x*e0.x + w.y*e0.y + w.z*e0.z + w.w*e0.w;
            a1 += w.x*e1.x + w.y*e1.y + w.z*e1.z + w.w*e1.w;
            a2 += w.x*e2.x + w.y*e2.y + w.z*e2.z + w.w*e2.w;
            a3 += w.x*e3.x + w.y*e3.y + w.z*e3.z + w.w*e3.w;
        }
        const float bb = bih[j] + bhh[j];
        xg[(long)(t0 + 0) * G4 + j] = a0 + bb;
        xg[(long)(t0 + 1) * G4 + j] = a1 + bb;
        xg[(long)(t0 + 2) * G4 + j] = a2 + bb;
        xg[(long)(t0 + 3) * G4 + j] = a3 + bb;
    }
}

// ---------------------------------------------------------------------------
// Kernel B: the serial LSTM recurrence. NBLK=16 persistent blocks, 256 thr.
// Block b owns h[b*16 .. b*16+16). Its 64 W_hh rows (4 gates x 16) live in
// registers: thread (part=tid>>6, r=tid&63) holds W_hh[row(r)][part*64..+64).
// Cross-block h exchange each step via h_all in global + device-scope
// release/acquire barrier on a per-step counter (XCD L2s are not coherent).
// ---------------------------------------------------------------------------
__global__ __launch_bounds__(256) void lstm_kernel(
    const float* __restrict__ Whh, const float* __restrict__ xg,
    float* __restrict__ h_all, unsigned int* __restrict__ cnt)
{
    const int tid  = threadIdx.x;
    const int b    = blockIdx.x;       // 0..NBLK-1
    const int part = tid >> 6;         // k-quarter 0..3
    const int r    = tid & 63;         // local row 0..63 (gate = r>>4, idx = r&15)
    const int grow = (r >> 4) * HID + b * SH + (r & 15);   // global W_hh row

    // register-resident weight slice: 64 floats / thread
    float4 w[16];
    const float4* wsrc = (const float4*)(Whh + (long)grow * HID + part * 64);
#pragma unroll
    for (int q = 0; q < 16; ++q) w[q] = wsrc[q];

    __shared__ __align__(16) float hbuf[HID];
    __shared__ float psum[4][65];      // +1 pad: 2-way max bank aliasing (free)
    __shared__ float carr[SH];

    hbuf[tid] = 0.f;                   // h_0 = 0
    if (tid < SH) carr[tid] = 0.f;     // c_0 = 0
    __syncthreads();

    for (int s = 0; s < TT; ++s) {
        // xg prefetch (independent of h -> overlaps with the dot)
        float xgv = 0.f;
        if (tid < 64) {
            const int j = (tid >> 4) * HID + b * SH + (tid & 15);
            xgv = xg[(long)s * G4 + j];
        }
        // partial dot over this thread's k-quarter
        const float4* h4 = (const float4*)(hbuf + part * 64);
        float p = 0.f;
#pragma unroll
        for (int q = 0; q < 16; ++q) {
            const float4 h = h4[q];
            p += w[q].x*h.x + w[q].y*h.y + w[q].z*h.z + w[q].w*h.w;
        }
        psum[part][r] = p;
        __syncthreads();

        if (tid < 64) {  // wave 0 exactly
            float g = psum[0][tid] + psum[1][tid] + psum[2][tid] + psum[3][tid] + xgv;
            // lane layout: lanes 0-15 = i, 16-31 = f, 32-47 = g, 48-63 = o
            const int hi = tid & 15;
            float gf = __shfl(g, hi + 16, 64);
            float gg = __shfl(g, hi + 32, 64);
            float go = __shfl(g, hi + 48, 64);
            if (tid < 16) {
                const float i_ = sigf(g);
                const float f_ = sigf(gf);
                const float g_ = tanhf_fast(gg);
                const float o_ = sigf(go);
                float c = f_ * carr[tid] + i_ * g_;
                carr[tid] = c;
                const float hn = o_ * tanhf_fast(c);
                h_all[(long)(s + 1) * HID + b * SH + tid] = hn;
            }
        }
        __syncthreads();   // drains wave 0's global h write (vmcnt(0) at barrier)

        if (tid == 0) {
            __hip_atomic_fetch_add(&cnt[s], 1u, __ATOMIC_RELEASE, __HIP_MEMORY_SCOPE_AGENT);
            while (__hip_atomic_load(&cnt[s], __ATOMIC_RELAXED, __HIP_MEMORY_SCOPE_AGENT) < NBLK) {}
            (void)__hip_atomic_load(&cnt[s], __ATOMIC_ACQUIRE, __HIP_MEMORY_SCOPE_AGENT);
        }
        __syncthreads();

        hbuf[tid] = h_all[(long)(s + 1) * HID + tid];   // fresh lines, post-acquire
        __syncthreads();
    }
}

// ---------------------------------------------------------------------------
// Kernel C: tag logits + log_softmax. One 64-thread block per token.
// ---------------------------------------------------------------------------
__global__ __launch_bounds__(64) void out_kernel(
    const float* __restrict__ h_all, const float* __restrict__ Wout,
    const float* __restrict__ bout, float* __restrict__ out)
{
    const int t   = blockIdx.x;
    const int tid = threadIdx.x;
    __shared__ __align__(16) float hs[HID];
    __shared__ float lg[NTAGS];

    ((float4*)hs)[tid] = ((const float4*)(h_all + (long)(t + 1) * HID))[tid];
    __syncthreads();

    if (tid < NTAGS) {
        const float4* wr = (const float4*)(Wout + (long)tid * HID);
        float p = 0.f;
#pragma unroll 8
        for (int q = 0; q < HID / 4; ++q) {
            const float4 w = wr[q];
            const float4 h = ((const float4*)hs)[q];
            p += w.x*h.x + w.y*h.y + w.z*h.z + w.w*h.w;
        }
        lg[tid] = p + bout[tid];
    }
    __syncthreads();

    if (tid < NTAGS) {
        float m = -1e30f;
        for (int g = 0; g < NTAGS; ++g) m = fmaxf(m, lg[g]);
        float ss = 0.f;
        for (int g = 0; g < NTAGS; ++g) ss += __expf(lg[g] - m);
        out[(long)t * NTAGS + tid] = lg[tid] - (m + __logf(ss));
    }
}

// ---------------------------------------------------------------------------
extern "C" void kernel_launch(void* const* d_in, const int* in_sizes, int n_in,
                              void* d_out, int out_size, void* d_ws, size_t ws_size,
                              hipStream_t stream)
{
    const int*   tok  = (const int*)  d_in[0];
    const float* emb  = (const float*)d_in[1];
    const float* Wih  = (const float*)d_in[2];
    const float* Whh  = (const float*)d_in[3];
    const float* bih  = (const float*)d_in[4];
    const float* bhh  = (const float*)d_in[5];
    const float* Wout = (const float*)d_in[6];
    const float* bout = (const float*)d_in[7];
    float* out = (float*)d_out;

    char* ws = (char*)d_ws;
    float*        xg    = (float*)(ws);                                       // 32 MB
    float*        h_all = (float*)(ws + (size_t)TT * G4 * 4);                 // 8.4 MB
    unsigned int* cnt   = (unsigned int*)(ws + (size_t)TT * G4 * 4
                                             + (size_t)(TT + 1) * HID * 4);   // 32 KB

    xg_kernel  <<<TT / 4, 256, 0, stream>>>(tok, emb, Wih, bih, bhh, xg, cnt);
    lstm_kernel<<<NBLK,   256, 0, stream>>>(Whh, xg, h_all, cnt);
    out_kernel <<<TT,     64,  0, stream>>>(h_all, Wout, bout, out);
}

// Round 3
// 18461.723 us; speedup vs baseline: 1.0471x; 1.0471x over previous
//
#include <hip/hip_runtime.h>
#include <stdint.h>

#define TT    8192
#define EMBD  128
#define HID   256
#define G4    1024      // 4*HID
#define NTAGS 17
#define NBLK  16        // recurrence blocks; block b owns h[b*16 .. b*16+16)
#define SH    16        // HID / NBLK
#define QW    68        // padded LDS stride per k-quarter (68*4B = 272B, 16B-aligned, conflict-free)

typedef unsigned int u32;

__device__ __forceinline__ float sigf(float x) { return 1.f / (1.f + __expf(-x)); }
__device__ __forceinline__ float tanhf_fast(float x) {
    x = fminf(15.f, fmaxf(-15.f, x));
    float a = __expf(2.f * x);
    return (a - 1.f) / (a + 1.f);
}

// ---------------------------------------------------------------------------
// Kernel A: xg[t][j] = dot(emb[tok[t]], W_ih[j]) + b_ih[j] + b_hh[j]
// (identical math to round 1's passing version; counter init removed)
// ---------------------------------------------------------------------------
__global__ __launch_bounds__(256) void xg_kernel(
    const int* __restrict__ tok, const float* __restrict__ emb,
    const float* __restrict__ Wih, const float* __restrict__ bih,
    const float* __restrict__ bhh, float* __restrict__ xg)
{
    __shared__ __align__(16) float es[4][EMBD];
    const int tid = threadIdx.x;
    const int t0  = blockIdx.x * 4;

    for (int p = tid; p < 4 * EMBD; p += 256) {
        const int tt = p >> 7, k = p & 127;
        es[tt][k] = emb[(long)tok[t0 + tt] * EMBD + k];
    }
    __syncthreads();

#pragma unroll
    for (int q = 0; q < 4; ++q) {
        const int j = q * 256 + tid;
        const float4* wr = (const float4*)(Wih + (long)j * EMBD);
        float a0 = 0.f, a1 = 0.f, a2 = 0.f, a3 = 0.f;
#pragma unroll 8
        for (int k4 = 0; k4 < EMBD / 4; ++k4) {
            const float4 w  = wr[k4];
            const float4 e0 = ((const float4*)es[0])[k4];
            const float4 e1 = ((const float4*)es[1])[k4];
            const float4 e2 = ((const float4*)es[2])[k4];
            const float4 e3 = ((const float4*)es[3])[k4];
            a0 += w.x*e0.x + w.y*e0.y + w.z*e0.z + w.w*e0.w;
            a1 += w.x*e1.x + w.y*e1.y + w.z*e1.z + w.w*e1.w;
            a2 += w.x*e2.x + w.y*e2.y + w.z*e2.z + w.w*e2.w;
            a3 += w.x*e3.x + w.y*e3.y + w.z*e3.z + w.w*e3.w;
        }
        const float bb = bih[j] + bhh[j];
        xg[(long)(t0 + 0) * G4 + j] = a0 + bb;
        xg[(long)(t0 + 1) * G4 + j] = a1 + bb;
        xg[(long)(t0 + 2) * G4 + j] = a2 + bb;
        xg[(long)(t0 + 3) * G4 + j] = a3 + bb;
    }
}

// ---------------------------------------------------------------------------
// Kernel B: LSTM recurrence, 16 blocks x 256 threads. No placement tricks.
// h exchange: one u32 word per h element per step, ((s+1)<<16) | bf16(h),
// written/read with RELAXED AGENT-scope atomics (coherence-point ops; the
// tag travels WITH the data so no fences/ordering needed; 0xAA poison and
// any prior-launch residue can never match a tag in [1,8192]).
//
// Lane layout (wave-autonomous, 1 barrier/step):
//   wave w (tid>>6) owns h indices b*16 + w*4 + {0..3}
//   lane L = tid&63: gate g=L>>4, h-sub hi=(L>>2)&3, k-quarter q=L&3
//   row = g*256 + b*16 + w*4 + hi ; thread holds W_hh[row][q*64..q*64+64)
//   in 16 float4 VGPRs. Dot partials reduced across q via 2 shfl_xor; gate
//   values gathered via 3 shfls; lanes (g==0,q==0) hold c and produce h.
// ---------------------------------------------------------------------------
__global__ __launch_bounds__(256) void lstm_kernel(
    const float* __restrict__ Whh, const float* __restrict__ xg,
    u32* __restrict__ hx)
{
    const int tid = threadIdx.x;
    const int b   = blockIdx.x;
    const int w   = tid >> 6;
    const int L   = tid & 63;
    const int g   = L >> 4;
    const int l15 = L & 15;
    const int hi  = l15 >> 2;
    const int q   = L & 3;
    const int row = g * HID + b * SH + w * 4 + hi;

    // register-resident W_hh slice: 64 floats/thread
    float4 wv[16];
    const float4* wsrc = (const float4*)(Whh + (long)row * HID + q * 64);
#pragma unroll
    for (int j = 0; j < 16; ++j) wv[j] = wsrc[j];

    __shared__ __align__(16) float hlds[2][4 * QW];
    for (int i = tid; i < 4 * QW; i += 256) hlds[0][i] = 0.f;   // h_0 = 0
    __syncthreads();

    float c_reg = 0.f;
    const bool leader = (g == 0) && (q == 0);      // lanes 0,4,8,12 per wave
    const int  gidx   = b * SH + w * 4 + hi;       // h index this leader produces
    const int  myslot = (tid >> 6) * QW + (tid & 63);   // consumer LDS slot

    const float* xgp = xg + row;

    // software prefetch of xg, 2 steps ahead (reads up to 2 rows past xg end,
    // which is the start of hx -- valid ws memory, values unused)
    float xg0 = xgp[0];
    float xg1 = xgp[G4];

    auto step = [&](int s, float xgv) {
        const int cur = s & 1;
        const float* hb = &hlds[cur][q * QW];
        float p0 = 0.f, p1 = 0.f, p2 = 0.f, p3 = 0.f;
#pragma unroll
        for (int j = 0; j < 16; ++j) {
            const float4 hv = *(const float4*)(hb + j * 4);
            p0 += wv[j].x * hv.x; p1 += wv[j].y * hv.y;
            p2 += wv[j].z * hv.z; p3 += wv[j].w * hv.w;
        }
        float p = (p0 + p1) + (p2 + p3);
        p += __shfl_xor(p, 1, 64);                 // reduce across q
        p += __shfl_xor(p, 2, 64);
        const float pre = p + xgv;
        const float vf = __shfl(pre, 16 + l15, 64);
        const float vg = __shfl(pre, 32 + l15, 64);
        const float vo = __shfl(pre, 48 + l15, 64);
        if (leader) {
            const float i_ = sigf(pre);
            const float f_ = sigf(vf);
            const float g_ = tanhf_fast(vg);
            const float o_ = sigf(vo);
            c_reg = f_ * c_reg + i_ * g_;
            const float hn = o_ * tanhf_fast(c_reg);
            u32 hb32 = __float_as_uint(hn);
            u32 rb   = (hb32 + 0x7FFFu + ((hb32 >> 16) & 1u)) >> 16;  // RNE bf16
            __hip_atomic_store(&hx[(long)(s + 1) * HID + gidx],
                               ((u32)(s + 1) << 16) | rb,
                               __ATOMIC_RELAXED, __HIP_MEMORY_SCOPE_AGENT);
            // own-block shortcut through LDS (same rounded value others see)
            hlds[cur ^ 1][(gidx >> 6) * QW + (gidx & 63)] =
                __uint_as_float(rb << 16);
        }
        // consume the other 240 h words (own 16 were written via LDS above)
        if ((tid >> 4) != b) {
            const u32 want = (u32)(s + 1) << 16;
            u32* wp = &hx[(long)(s + 1) * HID + tid];
            u32 u;
            do { u = __hip_atomic_load(wp, __ATOMIC_RELAXED,
                                       __HIP_MEMORY_SCOPE_AGENT); }
            while ((u & 0xFFFF0000u) != want);
            hlds[cur ^ 1][myslot] = __uint_as_float(u << 16);
        }
        __syncthreads();
    };

    for (int s = 0; s < TT; s += 2) {
        const float xgn0 = xgp[(long)(s + 2) * G4];
        step(s, xg0);
        const float xgn1 = xgp[(long)(s + 3) * G4];
        step(s + 1, xg1);
        xg0 = xgn0; xg1 = xgn1;
    }
}

// ---------------------------------------------------------------------------
// Kernel C: tag logits + log_softmax; unpacks bf16 h from the tagged words.
// ---------------------------------------------------------------------------
__global__ __launch_bounds__(64) void out_kernel(
    const u32* __restrict__ hx, const float* __restrict__ Wout,
    const float* __restrict__ bout, float* __restrict__ out)
{
    const int t   = blockIdx.x;
    const int tid = threadIdx.x;
    __shared__ __align__(16) float hs[HID];
    __shared__ float lg[NTAGS];

    const uint4 uu = ((const uint4*)(hx + (long)(t + 1) * HID))[tid];
    hs[tid * 4 + 0] = __uint_as_float(uu.x << 16);
    hs[tid * 4 + 1] = __uint_as_float(uu.y << 16);
    hs[tid * 4 + 2] = __uint_as_float(uu.z << 16);
    hs[tid * 4 + 3] = __uint_as_float(uu.w << 16);
    __syncthreads();

    if (tid < NTAGS) {
        const float4* wr = (const float4*)(Wout + (long)tid * HID);
        float p = 0.f;
#pragma unroll 8
        for (int qq = 0; qq < HID / 4; ++qq) {
            const float4 w = wr[qq];
            const float4 h = ((const float4*)hs)[qq];
            p += w.x*h.x + w.y*h.y + w.z*h.z + w.w*h.w;
        }
        lg[tid] = p + bout[tid];
    }
    __syncthreads();

    if (tid < NTAGS) {
        float m = -1e30f;
        for (int gg = 0; gg < NTAGS; ++gg) m = fmaxf(m, lg[gg]);
        float ss = 0.f;
        for (int gg = 0; gg < NTAGS; ++gg) ss += __expf(lg[gg] - m);
        out[(long)t * NTAGS + tid] = lg[tid] - (m + __logf(ss));
    }
}

// ---------------------------------------------------------------------------
extern "C" void kernel_launch(void* const* d_in, const int* in_sizes, int n_in,
                              void* d_out, int out_size, void* d_ws, size_t ws_size,
                              hipStream_t stream)
{
    const int*   tok  = (const int*)  d_in[0];
    const float* emb  = (const float*)d_in[1];
    const float* Wih  = (const float*)d_in[2];
    const float* Whh  = (const float*)d_in[3];
    const float* bih  = (const float*)d_in[4];
    const float* bhh  = (const float*)d_in[5];
    const float* Wout = (const float*)d_in[6];
    const float* bout = (const float*)d_in[7];
    float* out = (float*)d_out;

    char* ws = (char*)d_ws;
    float* xg = (float*)(ws);                        // 33,554,432 B
    u32*   hx = (u32*)  (ws + 33554432UL);           //  8,389,632 B  (total 41.94 MB)

    xg_kernel  <<<TT / 4, 256, 0, stream>>>(tok, emb, Wih, bih, bhh, xg);
    lstm_kernel<<<NBLK,   256, 0, stream>>>(Whh, xg, hx);
    out_kernel <<<TT,     64,  0, stream>>>(hx, Wout, bout, out);
}